// Round 5
// baseline (504.728 us; speedup 1.0000x reference)
//
#include <hip/hip_runtime.h>
#include <math.h>

#define Bb 2
#define Nn 32768
#define Cc 128
#define Ff 128
#define LL 4
#define SKN 128
#define PS 16448   // Spart plane stride (floats): 16384+64 breaks power-of-2 channel aliasing
#define TWOPI 6.283185307179586f

typedef __attribute__((ext_vector_type(8))) short short8;
typedef __attribute__((ext_vector_type(4))) float float4v;
typedef __attribute__((ext_vector_type(2))) unsigned int uint2v;
typedef unsigned short ushort_t;
typedef unsigned int uint_t;

union frag_cast { short8 s; uint_t u[4]; };
union vec8 { float4v v[2]; float s[8]; };

__device__ inline uint_t asu(float f) { union { float f; uint_t u; } x; x.f = f; return x.u; }
__device__ inline float asf(uint_t u) { union { uint_t u; float f; } x; x.u = u; return x.f; }
// pack: low16 = bf16-trunc(v0), high16 = bf16-trunc(v1)
__device__ inline uint_t pack_hi(float v0, float v1) { return (asu(v0) >> 16) | (asu(v1) & 0xffff0000u); }
// exact residual after bf16 truncation
__device__ inline float resid(float v) { return v - asf(asu(v) & 0xffff0000u); }

// ---------------- prep: transpose x,y -> [b][d][n] planes
__global__ __launch_bounds__(256) void prep_xt(const float* __restrict__ x,
                                               const float* __restrict__ y,
                                               float* __restrict__ xT,
                                               float* __restrict__ yT) {
    int i = blockIdx.x * 256 + threadIdx.x;        // b*Nn + n
    int b = i >> 15, n = i & 32767;
    const float* xp = x + (size_t)i * 3;
    const float* yp = y + (size_t)i * 3;
    size_t base = ((size_t)(b * 3) << 15) + n;
    xT[base] = xp[0]; xT[base + (1 << 15)] = xp[1]; xT[base + (2 << 15)] = xp[2];
    yT[base] = yp[0]; yT[base + (1 << 15)] = yp[1]; yT[base + (2 << 15)] = yp[2];
}

// ---------------- in projection -> packed bf16 hi/lo planes hfTh/hfTl[b][c][n-pair]
__global__ __launch_bounds__(256) void in_proj(const float* __restrict__ a,
                                               const float* __restrict__ w,
                                               const float* __restrict__ bias,
                                               uint_t* __restrict__ hfTh,
                                               uint_t* __restrict__ hfTl) {
    int idx = blockIdx.x * 256 + threadIdx.x;      // b*C*(N/2) + c*(N/2) + np
    int np = idx & 16383;
    int c = (idx >> 14) & 127;
    int b = idx >> 21;
    int n = np * 2;
    const float* ap = a + (((size_t)(b << 15)) + n) * 4;
    float s0 = bias[c], s1 = s0;
#pragma unroll
    for (int i = 0; i < 4; ++i) { s0 += ap[i] * w[i * Cc + c]; s1 += ap[4 + i] * w[i * Cc + c]; }
    hfTh[idx] = pack_hi(s0, s1);
    hfTl[idx] = pack_hi(resid(s0), resid(s1));
}

// ---------------- forward transform: barrier-free, zero-LDS, h-fused in block.
// Spart[b,h,sk][c][f] = sum_{n in chunk} hf[b][c][n] * trig_h(x[n]·k2pi[f])
// 512 thr = 8 waves: (wm 2 c-halves) x (wn 2 f-halves) x (h 2)
__global__ __launch_bounds__(512, 4) void fwd_bf(const uint_t* __restrict__ hfTh,
                                                 const uint_t* __restrict__ hfTl,
                                                 const float* __restrict__ xT,
                                                 const float* __restrict__ freqs,
                                                 float* __restrict__ Spart) {
    const int sk = blockIdx.x, ct = blockIdx.y, b = blockIdx.z;
    const int n0 = sk * (Nn / SKN);                // 256-point chunk
    const int tid = threadIdx.x, lane = tid & 63, wave = tid >> 6;
    const int h = wave & 1, wn = (wave >> 1) & 1, wm = wave >> 2;
    const int fr = lane & 15, kg = lane >> 4;

    // per-lane fixed frequencies (pre-scaled by 2pi) for the 4 B-frag columns
    float kx[4], ky[4], kz[4];
#pragma unroll
    for (int ni = 0; ni < 4; ++ni) {
        int f = wn * 64 + ni * 16 + fr;
        kx[ni] = TWOPI * freqs[f * 3 + 0];
        ky[ni] = TWOPI * freqs[f * 3 + 1];
        kz[ni] = TWOPI * freqs[f * 3 + 2];
    }

    const float* xb = xT + ((size_t)(b * 3) << 15);
    const int crow0 = b * 128 + ct * 64 + wm * 32;

    float4v acc[2][4];
#pragma unroll
    for (int mi = 0; mi < 2; ++mi)
#pragma unroll
        for (int ni = 0; ni < 4; ++ni) acc[mi][ni] = (float4v){0.f, 0.f, 0.f, 0.f};

    for (int kt = 0; kt < Nn / SKN; kt += 32) {
        const int nbase = n0 + kt + kg * 8;        // this lane's 8 k-points
        vec8 X0, X1, X2;
        X0.v[0] = *(const float4v*)(xb + nbase);
        X0.v[1] = *(const float4v*)(xb + nbase + 4);
        X1.v[0] = *(const float4v*)(xb + (1 << 15) + nbase);
        X1.v[1] = *(const float4v*)(xb + (1 << 15) + nbase + 4);
        X2.v[0] = *(const float4v*)(xb + (2 << 15) + nbase);
        X2.v[1] = *(const float4v*)(xb + (2 << 15) + nbase + 4);

        frag_cast bh[4], bl[4];
#pragma unroll
        for (int ni = 0; ni < 4; ++ni)
#pragma unroll
            for (int q = 0; q < 4; ++q) {
                float a0 = X0.s[2 * q] * kx[ni] + X1.s[2 * q] * ky[ni] + X2.s[2 * q] * kz[ni];
                float a1 = X0.s[2 * q + 1] * kx[ni] + X1.s[2 * q + 1] * ky[ni] + X2.s[2 * q + 1] * kz[ni];
                float v0 = h ? __sinf(a0) : __cosf(a0);
                float v1 = h ? __sinf(a1) : __cosf(a1);
                bh[ni].u[q] = pack_hi(v0, v1);
                bl[ni].u[q] = pack_hi(resid(v0), resid(v1));
            }

#pragma unroll
        for (int mi = 0; mi < 2; ++mi) {
            const size_t rowoff = ((size_t)(crow0 + mi * 16 + fr) << 14) + (nbase >> 1);
            frag_cast ah, al;
            ah.s = *(const short8*)(hfTh + rowoff);
            al.s = *(const short8*)(hfTl + rowoff);
#pragma unroll
            for (int ni = 0; ni < 4; ++ni) {
                acc[mi][ni] = __builtin_amdgcn_mfma_f32_16x16x32_bf16(ah.s, bh[ni].s, acc[mi][ni], 0, 0, 0);
                acc[mi][ni] = __builtin_amdgcn_mfma_f32_16x16x32_bf16(ah.s, bl[ni].s, acc[mi][ni], 0, 0, 0);
                acc[mi][ni] = __builtin_amdgcn_mfma_f32_16x16x32_bf16(al.s, bh[ni].s, acc[mi][ni], 0, 0, 0);
            }
        }
    }

    float* op = Spart + (size_t)((b * 2 + h) * SKN + sk) * PS;
#pragma unroll
    for (int mi = 0; mi < 2; ++mi)
#pragma unroll
        for (int ni = 0; ni < 4; ++ni)
#pragma unroll
            for (int r = 0; r < 4; ++r) {
                int c = ct * 64 + wm * 32 + mi * 16 + kg * 4 + r;
                int f = wn * 64 + ni * 16 + fr;
                op[c * 128 + f] = acc[mi][ni][r];
            }
}

// ---------------- reduce split-K partials: S[bh][c][f] = sum_sk Spart (padded stride)
__global__ __launch_bounds__(256) void reduce_kernel(const float* __restrict__ Spart,
                                                     float* __restrict__ S) {
    int idx = blockIdx.x * 256 + threadIdx.x;
    int bh = idx >> 14, cf = idx & 16383;
    const float* p = Spart + (size_t)bh * SKN * PS + cf;
    float s = 0.0f;
#pragma unroll 8
    for (int k = 0; k < SKN; ++k) s += p[(size_t)k * PS];
    S[idx] = s;
}

// ---------------- channel mixing -> packed bf16 hi/lo G planes (both b per block, W read once)
__global__ __launch_bounds__(256) void mix_kernel(const float* __restrict__ S,
                                                  const float* __restrict__ Wre,
                                                  const float* __restrict__ Wim,
                                                  uint_t* __restrict__ Gh,
                                                  uint_t* __restrict__ Gl) {
    __shared__ float Stile[4][128][16];            // [b*2+h][c][f-local], 32 KB
    const int ot = blockIdx.x;                     // 32 tiles of 4 o
    const int ft = blockIdx.y;                     // 8 tiles of 16 f
    const int tid = threadIdx.x;
    const int fl = tid & 15, ol = (tid >> 4) & 3, cg = tid >> 6;
    const int o = ot * 4 + ol, f0 = ft * 16;

    for (int i = tid; i < 8192; i += 256) {
        int bh = i >> 11, c = (i >> 4) & 127, ff = i & 15;
        Stile[bh][c][ff] = S[(size_t)bh * 16384 + c * 128 + f0 + ff];
    }
    __syncthreads();

    float g0 = 0.f, g1 = 0.f, g2 = 0.f, g3 = 0.f;  // gre_b0, gmi_b0, gre_b1, gmi_b1
#pragma unroll 4
    for (int c = cg * 32; c < cg * 32 + 32; ++c) {
        float wr = Wre[((size_t)(c * 128 + o)) * 128 + f0 + fl];
        float wi = Wim[((size_t)(c * 128 + o)) * 128 + f0 + fl];
        float sc0 = Stile[0][c][fl], ss0 = Stile[1][c][fl];
        float sc1 = Stile[2][c][fl], ss1 = Stile[3][c][fl];
        g0 += sc0 * wr + ss0 * wi;  g1 += ss0 * wr - sc0 * wi;
        g2 += sc1 * wr + ss1 * wi;  g3 += ss1 * wr - sc1 * wi;
    }
    __syncthreads();
    float4v* rp = (float4v*)Stile;                 // reuse LDS for cross-cg reduce
    rp[cg * 64 + ol * 16 + fl] = (float4v){g0, g1, g2, g3};
    __syncthreads();
    if (cg == 0) {
        float4v r = rp[ol * 16 + fl];
        r += rp[64 + ol * 16 + fl];
        r += rp[128 + ol * 16 + fl];
        r += rp[192 + ol * 16 + fl];
        const float invN = 1.0f / (float)Nn;
        float gre0 = r[0] * invN, gmi0 = r[1] * invN;
        float gre1 = r[2] * invN, gmi1 = r[3] * invN;
        Gh[(0 * 128 + o) * 128 + f0 + fl] = pack_hi(gre0, gmi0);
        Gl[(0 * 128 + o) * 128 + f0 + fl] = pack_hi(resid(gre0), resid(gmi0));
        Gh[(1 * 128 + o) * 128 + f0 + fl] = pack_hi(gre1, gmi1);
        Gl[(1 * 128 + o) * 128 + f0 + fl] = pack_hi(resid(gre1), resid(gmi1));
    }
}

// ---------------- inverse evaluation + gelu: freqs in LDS, n-tile 64, 4 blocks/CU.
// k = 2f+h: even k -> cos*Gre, odd k -> sin*Gmi. Output packed into hfTh/hfTl.
__global__ __launch_bounds__(256, 4) void inv_bf(const uint_t* __restrict__ Gh,
                                                 const uint_t* __restrict__ Gl,
                                                 const float* __restrict__ ptsT,
                                                 const float* __restrict__ freqs,
                                                 uint_t* __restrict__ hfTh,
                                                 uint_t* __restrict__ hfTl) {
    __shared__ __align__(16) float kxs[128], kys[128], kzs[128];
    const int nt = blockIdx.x, b = blockIdx.y;
    const int n0 = nt * 64;
    const int tid = threadIdx.x, lane = tid & 63, wave = tid >> 6;
    const int wm = wave & 1, wn = wave >> 1;       // 2 n-halves x 2 o-halves
    const int fr = lane & 15, kg = lane >> 4;

    if (tid < 128) {
        kxs[tid] = TWOPI * freqs[tid * 3 + 0];
        kys[tid] = TWOPI * freqs[tid * 3 + 1];
        kzs[tid] = TWOPI * freqs[tid * 3 + 2];
    }

    const float* pb = ptsT + ((size_t)(b * 3) << 15);
    float px[2], py[2], pz[2];
#pragma unroll
    for (int mi = 0; mi < 2; ++mi) {
        int n = n0 + wm * 32 + mi * 16 + fr;
        px[mi] = pb[n]; py[mi] = pb[(1 << 15) + n]; pz[mi] = pb[(2 << 15) + n];
    }
    __syncthreads();

    float4v acc[2][4];
#pragma unroll
    for (int mi = 0; mi < 2; ++mi)
#pragma unroll
        for (int ni = 0; ni < 4; ++ni) acc[mi][ni] = (float4v){0.f, 0.f, 0.f, 0.f};

#pragma unroll
    for (int kt = 0; kt < 8; ++kt) {
        const int fbase = kt * 16 + kg * 4;
        float4v kxv = *(const float4v*)&kxs[fbase];
        float4v kyv = *(const float4v*)&kys[fbase];
        float4v kzv = *(const float4v*)&kzs[fbase];

        frag_cast bh[4], bl[4];
#pragma unroll
        for (int ni = 0; ni < 4; ++ni) {
            size_t gi = ((size_t)(b * 128 + wn * 64 + ni * 16 + fr)) * 128 + fbase;
            bh[ni].s = *(const short8*)(Gh + gi);
            bl[ni].s = *(const short8*)(Gl + gi);
        }
#pragma unroll
        for (int mi = 0; mi < 2; ++mi) {
            frag_cast ah, al;
#pragma unroll
            for (int q = 0; q < 4; ++q) {
                float ang = px[mi] * kxv[q] + py[mi] * kyv[q] + pz[mi] * kzv[q];
                float cv = __cosf(ang), sv = __sinf(ang);
                ah.u[q] = pack_hi(cv, sv);
                al.u[q] = pack_hi(resid(cv), resid(sv));
            }
#pragma unroll
            for (int ni = 0; ni < 4; ++ni) {
                acc[mi][ni] = __builtin_amdgcn_mfma_f32_16x16x32_bf16(ah.s, bh[ni].s, acc[mi][ni], 0, 0, 0);
                acc[mi][ni] = __builtin_amdgcn_mfma_f32_16x16x32_bf16(ah.s, bl[ni].s, acc[mi][ni], 0, 0, 0);
                acc[mi][ni] = __builtin_amdgcn_mfma_f32_16x16x32_bf16(al.s, bh[ni].s, acc[mi][ni], 0, 0, 0);
            }
        }
    }

    // epilogue: gelu (tanh approx via expf) + packed bf16 hi/lo store
#pragma unroll
    for (int mi = 0; mi < 2; ++mi)
#pragma unroll
        for (int ni = 0; ni < 4; ++ni) {
            float g[4];
#pragma unroll
            for (int r = 0; r < 4; ++r) {
                float v = acc[mi][ni][r];
                float u2 = 1.5957691216057308f * (v + 0.044715f * v * v * v);
                float t = 1.0f - 2.0f / (1.0f + __expf(u2));
                g[r] = 0.5f * v * (1.0f + t);
            }
            int o = wn * 64 + ni * 16 + fr;
            int nb = n0 + wm * 32 + mi * 16 + kg * 4;
            size_t di = ((size_t)(b * 128 + o) << 14) + (nb >> 1);
            uint2v hv = { pack_hi(g[0], g[1]), pack_hi(g[2], g[3]) };
            uint2v lv = { pack_hi(resid(g[0]), resid(g[1])), pack_hi(resid(g[2]), resid(g[3])) };
            *(uint2v*)(hfTh + di) = hv;
            *(uint2v*)(hfTl + di) = lv;
        }
}

// ---------------- out projection (reads packed hfT planes)
__global__ __launch_bounds__(256) void out_proj(const uint_t* __restrict__ hfTh,
                                                const uint_t* __restrict__ hfTl,
                                                const float* __restrict__ w,
                                                const float* __restrict__ bias,
                                                float* __restrict__ u) {
    int i = blockIdx.x * 256 + threadIdx.x;        // b*(N/2) + np
    int b = i >> 14, np = i & 16383;
    const uint_t* hp = hfTh + ((size_t)(b * 128) << 14) + np;
    const uint_t* lp = hfTl + ((size_t)(b * 128) << 14) + np;
    float s0a = bias[0], s1a = bias[1], s0b = bias[0], s1b = bias[1];
#pragma unroll 4
    for (int c = 0; c < 128; ++c) {
        uint_t hv = hp[(size_t)c << 14], lv = lp[(size_t)c << 14];
        float v0 = asf(hv << 16) + asf(lv << 16);
        float v1 = asf(hv & 0xffff0000u) + asf(lv & 0xffff0000u);
        float w0 = w[c * 2 + 0], w1 = w[c * 2 + 1];
        s0a += v0 * w0; s1a += v0 * w1;
        s0b += v1 * w0; s1b += v1 * w1;
    }
    float4v o4 = {s0a, s1a, s0b, s1b};
    *(float4v*)(u + ((size_t)(b << 15) + np * 2) * 2) = o4;
}

extern "C" void kernel_launch(void* const* d_in, const int* in_sizes, int n_in,
                              void* d_out, int out_size, void* d_ws, size_t ws_size,
                              hipStream_t stream) {
    const float* a        = (const float*)d_in[0];
    const float* x        = (const float*)d_in[1];
    const float* y        = (const float*)d_in[2];
    const float* fc_in_w  = (const float*)d_in[3];
    const float* fc_in_b  = (const float*)d_in[4];
    const float* freqs    = (const float*)d_in[5];
    const float* w_real   = (const float*)d_in[6];
    const float* w_imag   = (const float*)d_in[7];
    const float* fc_out_w = (const float*)d_in[8];
    const float* fc_out_b = (const float*)d_in[9];
    float* out = (float*)d_out;

    uint_t* ws    = (uint_t*)d_ws;
    uint_t* hfTh  = ws;                                        // B*C*N/2 = 4,194,304 dwords
    uint_t* hfTl  = hfTh + (size_t)Bb * Cc * Nn / 2;           // 4,194,304
    float*  Spart = (float*)(hfTl + (size_t)Bb * Cc * Nn / 2); // B*2*SKN*PS = 8,421,376 floats
    float*  S     = Spart + (size_t)Bb * 2 * SKN * PS;         // 65,536
    uint_t* Gh    = (uint_t*)(S + (size_t)Bb * 2 * Cc * Ff);   // 32,768
    uint_t* Gl    = Gh + (size_t)Bb * Cc * Ff;                 // 32,768
    float*  xT    = (float*)(Gl + (size_t)Bb * Cc * Ff);       // 196,608 floats
    float*  yT    = xT + (size_t)Bb * 3 * Nn;                  // 196,608

    prep_xt<<<(Bb * Nn) / 256, 256, 0, stream>>>(x, y, xT, yT);
    in_proj<<<(Bb * Cc * Nn / 2) / 256, 256, 0, stream>>>(a, fc_in_w, fc_in_b, hfTh, hfTl);

    for (int l = 0; l < LL; ++l) {
        const float* k   = freqs  + (size_t)l * Ff * 3;
        const float* Wre = w_real + (size_t)l * Cc * Cc * Ff;
        const float* Wim = w_imag + (size_t)l * Cc * Cc * Ff;
        const float* pT  = (l < LL - 1) ? xT : yT;

        fwd_bf<<<dim3(SKN, 2, Bb), 512, 0, stream>>>(hfTh, hfTl, xT, k, Spart);
        reduce_kernel<<<(Bb * 2 * Cc * Ff) / 256, 256, 0, stream>>>(Spart, S);
        mix_kernel<<<dim3(32, 8), 256, 0, stream>>>(S, Wre, Wim, Gh, Gl);
        inv_bf<<<dim3(Nn / 64, Bb), 256, 0, stream>>>(Gh, Gl, pT, k, hfTh, hfTl);
    }

    out_proj<<<(Bb * Nn / 2) / 256, 256, 0, stream>>>(hfTh, hfTl, fc_out_w, fc_out_b, out);
}